// Round 2
// baseline (212.755 us; speedup 1.0000x reference)
//
#include <hip/hip_runtime.h>
#include <stdint.h>

typedef __attribute__((ext_vector_type(8))) short bf16x8;
typedef __attribute__((ext_vector_type(4))) float f32x4;

__device__ __forceinline__ unsigned short bf16_of(float f) {
  union { float f; uint32_t u; } x; x.f = f;
  uint32_t r = x.u + 0x7fffu + ((x.u >> 16) & 1u);
  return (unsigned short)(r >> 16);
}

#define GLD16(gp, lp) __builtin_amdgcn_global_load_lds( \
    (const __attribute__((address_space(1))) uint32_t*)(gp), \
    (__attribute__((address_space(3))) uint32_t*)(lp), 16, 0, 0)

#define BAR() do { asm volatile("" ::: "memory"); __builtin_amdgcn_s_barrier(); asm volatile("" ::: "memory"); } while (0)

// ---------------- f32 -> bf16 convert (vectorized) ----------------
__global__ void cvt_f32_bf16(const float* __restrict__ src,
                             unsigned short* __restrict__ dst, int n4) {
  int i = blockIdx.x * blockDim.x + threadIdx.x;
  int stride = gridDim.x * blockDim.x;
  for (int j = i; j < n4; j += stride) {
    float4 f = ((const float4*)src)[j];
    union { unsigned short s[4]; uint2 v; } u;
    u.s[0] = bf16_of(f.x); u.s[1] = bf16_of(f.y);
    u.s[2] = bf16_of(f.z); u.s[3] = bf16_of(f.w);
    ((uint2*)dst)[j] = u.v;
  }
}

// ---------------- 256x256 8-phase GEMM: C[M,N] = A[M,K] * B[N,K]^T ----------
// 8 waves (2M x 4N), BK=64, 128KB LDS double-buffer, counted vmcnt pipeline.
// Per-wave frags interleaved: M-frag j at rows 32j+16wm, N-frag l at cols 64l+16wn.
// Quadrants per K-tile: Q1(A0,B0) Q2(A0,B1) Q3(A1,B1) Q4(A1,B0).
// Stage slots: A1(t+1)@ph0, B0(t+1)@ph1, A0(t+2)@ph2, B1(t+2)@ph3; vmcnt(4) @ end ph3.
template<int BIAS, int OUTF32>
__global__ __launch_bounds__(512, 2)
void gemm256(const unsigned short* __restrict__ A,
             const unsigned short* __restrict__ B,
             void* __restrict__ C, const float* __restrict__ bias,
             int M, int N, int K)
{
  __shared__ __align__(1024) unsigned short sm[65536];  // 128 KB
  char* const smb = (char*)sm;
  const int tid = threadIdx.x, w = tid >> 6, lane = tid & 63;
  const int wm = w >> 2, wn = w & 3;
  const int fr = lane & 15, kg = lane >> 4;
  const int swz = (fr & 7) << 4;
  const int srow = lane >> 3, sslot = lane & 7;

  const int nbx = N >> 8;
  const int nwg = gridDim.x;
  const int bid = blockIdx.x;
  const int bid2 = (bid & 7) * (nwg >> 3) + (bid >> 3);
  const int bm0 = (bid2 / nbx) << 8;
  const int bn0 = (bid2 % nbx) << 8;
  const int NT = K >> 6;

  f32x4 acc[8][4] = {};

  // stage one 16KB half-tile (2 x GLD16 per thread)
  auto STAGE = [&](int buf, int opnd, int half, int kt) {
    const unsigned short* G = opnd ? B : A;
    const int grow0 = opnd ? bn0 : bm0;
    char* region = smb + opnd * 65536 + buf * 32768 + half * 16384;
    const int k0 = kt << 6;
    #pragma unroll
    for (int i = 0; i < 2; ++i) {
      const int c = i * 8 + w;                    // 1KB chunk, wave-uniform
      const int row = half * 128 + c * 8 + srow;  // row&7 == srow
      const int slot = sslot ^ srow;              // pre-swizzled source slot
      GLD16(G + (size_t)(grow0 + row) * K + k0 + slot * 8, region + c * 1024);
    }
  };
  auto LDA = [&](char* Ab, int j, int ks) -> bf16x8 {
    const int r = 32 * j + 16 * wm + fr;
    return *(const bf16x8*)(Ab + r * 128 + ((ks * 64 + kg * 16) ^ swz));
  };
  auto LDB = [&](char* Bb, int l, int ks) -> bf16x8 {
    const int r = 64 * l + 16 * wn + fr;
    return *(const bf16x8*)(Bb + r * 128 + ((ks * 64 + kg * 16) ^ swz));
  };

  // prologue: tile0 all 4 halves + tile1 {A0,B1}; then wait leaving tile1 pair in flight
  STAGE(0, 0, 0, 0);            // A0(0)
  STAGE(0, 1, 1, 0);            // B1(0)
  STAGE(0, 0, 1, 0);            // A1(0)
  STAGE(0, 1, 0, 0);            // B0(0)
  if (NT > 1) {
    STAGE(1, 0, 0, 1);          // A0(1)
    STAGE(1, 1, 1, 1);          // B1(1)
    asm volatile("s_waitcnt vmcnt(4)" ::: "memory");
  } else {
    asm volatile("s_waitcnt vmcnt(0)" ::: "memory");
  }
  BAR();

  for (int t = 0; t < NT; ++t) {
    char* Ab = smb + (t & 1) * 32768;
    char* Bb = smb + 65536 + (t & 1) * 32768;
    bf16x8 a[4][2], b[2][2];

    // ---- phase 0: Q1 = A-half0 x B-half0
    #pragma unroll
    for (int j = 0; j < 4; ++j) { a[j][0] = LDA(Ab, j, 0); a[j][1] = LDA(Ab, j, 1); }
    #pragma unroll
    for (int l = 0; l < 2; ++l) { b[l][0] = LDB(Bb, l, 0); b[l][1] = LDB(Bb, l, 1); }
    if (t + 1 < NT) STAGE((t + 1) & 1, 0, 1, t + 1);   // A1(t+1)
    BAR();
    __builtin_amdgcn_s_setprio(1);
    #pragma unroll
    for (int j = 0; j < 4; ++j)
      #pragma unroll
      for (int l = 0; l < 2; ++l) {
        acc[j][l] = __builtin_amdgcn_mfma_f32_16x16x32_bf16(a[j][0], b[l][0], acc[j][l], 0, 0, 0);
        acc[j][l] = __builtin_amdgcn_mfma_f32_16x16x32_bf16(a[j][1], b[l][1], acc[j][l], 0, 0, 0);
      }
    __builtin_amdgcn_s_setprio(0);
    BAR();

    // ---- phase 1: Q2 = A-half0 x B-half1
    #pragma unroll
    for (int l = 0; l < 2; ++l) { b[l][0] = LDB(Bb, l + 2, 0); b[l][1] = LDB(Bb, l + 2, 1); }
    if (t + 1 < NT) STAGE((t + 1) & 1, 1, 0, t + 1);   // B0(t+1)
    BAR();
    __builtin_amdgcn_s_setprio(1);
    #pragma unroll
    for (int j = 0; j < 4; ++j)
      #pragma unroll
      for (int l = 0; l < 2; ++l) {
        acc[j][l + 2] = __builtin_amdgcn_mfma_f32_16x16x32_bf16(a[j][0], b[l][0], acc[j][l + 2], 0, 0, 0);
        acc[j][l + 2] = __builtin_amdgcn_mfma_f32_16x16x32_bf16(a[j][1], b[l][1], acc[j][l + 2], 0, 0, 0);
      }
    __builtin_amdgcn_s_setprio(0);
    BAR();

    // ---- phase 2: Q3 = A-half1 x B-half1
    #pragma unroll
    for (int j = 0; j < 4; ++j) { a[j][0] = LDA(Ab, j + 4, 0); a[j][1] = LDA(Ab, j + 4, 1); }
    if (t + 2 < NT) STAGE(t & 1, 0, 0, t + 2);         // A0(t+2)
    BAR();
    __builtin_amdgcn_s_setprio(1);
    #pragma unroll
    for (int j = 0; j < 4; ++j)
      #pragma unroll
      for (int l = 0; l < 2; ++l) {
        acc[j + 4][l + 2] = __builtin_amdgcn_mfma_f32_16x16x32_bf16(a[j][0], b[l][0], acc[j + 4][l + 2], 0, 0, 0);
        acc[j + 4][l + 2] = __builtin_amdgcn_mfma_f32_16x16x32_bf16(a[j][1], b[l][1], acc[j + 4][l + 2], 0, 0, 0);
      }
    __builtin_amdgcn_s_setprio(0);
    BAR();

    // ---- phase 3: Q4 = A-half1 x B-half0
    #pragma unroll
    for (int l = 0; l < 2; ++l) { b[l][0] = LDB(Bb, l, 0); b[l][1] = LDB(Bb, l, 1); }
    if (t + 2 < NT) STAGE(t & 1, 1, 1, t + 2);         // B1(t+2)
    BAR();
    __builtin_amdgcn_s_setprio(1);
    #pragma unroll
    for (int j = 0; j < 4; ++j)
      #pragma unroll
      for (int l = 0; l < 2; ++l) {
        acc[j + 4][l] = __builtin_amdgcn_mfma_f32_16x16x32_bf16(a[j][0], b[l][0], acc[j + 4][l], 0, 0, 0);
        acc[j + 4][l] = __builtin_amdgcn_mfma_f32_16x16x32_bf16(a[j][1], b[l][1], acc[j + 4][l], 0, 0, 0);
      }
    __builtin_amdgcn_s_setprio(0);
    // boundary wait: tile t+1's halves (last = B0(t+1)@phase1) must be landed;
    // allowed in flight: A0(t+2)@ph2, B1(t+2)@ph3 (2 halves = 4 loads)
    if (t + 2 < NT) { asm volatile("s_waitcnt vmcnt(4)" ::: "memory"); }
    else            { asm volatile("s_waitcnt vmcnt(0)" ::: "memory"); }
    BAR();
  }

  // epilogue: C/D layout col = lane&15, row = (lane>>4)*4 + reg
  #pragma unroll
  for (int l = 0; l < 4; ++l) {
    const int col = bn0 + 64 * l + 16 * wn + fr;
    float bb = 0.0f;
    if (BIAS && OUTF32) bb = bias[col];
    #pragma unroll
    for (int j = 0; j < 8; ++j) {
      const int row0 = bm0 + 32 * j + 16 * wm + kg * 4;
      #pragma unroll
      for (int rr = 0; rr < 4; ++rr) {
        if (OUTF32)
          ((float*)C)[(size_t)(row0 + rr) * N + col] = acc[j][l][rr] + bb;
        else
          ((unsigned short*)C)[(size_t)(row0 + rr) * N + col] = bf16_of(acc[j][l][rr]);
      }
    }
  }
}

// ---------------- block-local attention: one (b,h,g) 64x64 block per WG ----
__global__ __launch_bounds__(256, 2)
void attn_block(const unsigned short* __restrict__ qkv,
                unsigned short* __restrict__ o)
{
  __shared__ __align__(1024) unsigned short Qs[64 * 64];
  __shared__ __align__(1024) unsigned short Ks[64 * 64];
  __shared__ __align__(1024) unsigned short Vt[64 * 64];
  __shared__ __align__(1024) unsigned short Ps[64 * 64];
  const int tid = threadIdx.x, w = tid >> 6, lane = tid & 63;
  const int g = blockIdx.x, h = blockIdx.y, b = blockIdx.z;
  const size_t mbase = (size_t)b * 4096 + (size_t)g * 64;
  const unsigned short* qg = qkv + mbase * 3072 + h * 64;
  const unsigned short* kgl = qkv + mbase * 3072 + 1024 + h * 64;
  const unsigned short* vg = qkv + mbase * 3072 + 2048 + h * 64;

  #pragma unroll
  for (int i = 0; i < 2; ++i) {
    const int chunk = i * 4 + w;
    const int row = chunk * 8 + (lane >> 3);
    const int c8 = (lane & 7) ^ (row & 7);
    GLD16(qg + (size_t)row * 3072 + c8 * 8, (char*)Qs + chunk * 1024);
    GLD16(kgl + (size_t)row * 3072 + c8 * 8, (char*)Ks + chunk * 1024);
  }
  #pragma unroll
  for (int i = 0; i < 2; ++i) {
    const int c = i * 256 + tid;
    const int n = c >> 3, d0 = (c & 7) * 8;
    bf16x8 v = *(const bf16x8*)(vg + (size_t)n * 3072 + d0);
    #pragma unroll
    for (int j = 0; j < 8; ++j) {
      const int d = d0 + j;
      const int bo = d * 128 + n * 2;
      *(unsigned short*)((char*)Vt + (bo ^ ((d & 7) << 4))) = (unsigned short)v[j];
    }
  }
  __syncthreads();

  const int fr = lane & 15, kg = lane >> 4;
  f32x4 s[4] = {};
  #pragma unroll
  for (int kt = 0; kt < 2; ++kt) {
    const int kb = kt * 64 + kg * 16;
    const int rq = w * 16 + fr;
    bf16x8 aq = *(const bf16x8*)((const char*)Qs + rq * 128 + (kb ^ ((rq & 7) << 4)));
    #pragma unroll
    for (int nf = 0; nf < 4; ++nf) {
      const int rk = nf * 16 + fr;
      bf16x8 bk = *(const bf16x8*)((const char*)Ks + rk * 128 + (kb ^ ((rk & 7) << 4)));
      s[nf] = __builtin_amdgcn_mfma_f32_16x16x32_bf16(aq, bk, s[nf], 0, 0, 0);
    }
  }

  const float scale = 0.125f;
  float inv[4];
  #pragma unroll
  for (int r = 0; r < 4; ++r) {
    float m0 = fmaxf(fmaxf(s[0][r], s[1][r]), fmaxf(s[2][r], s[3][r]));
    #pragma unroll
    for (int d = 1; d < 16; d <<= 1) m0 = fmaxf(m0, __shfl_xor(m0, d));
    float sum = 0.0f;
    #pragma unroll
    for (int nf = 0; nf < 4; ++nf) {
      float p = __expf((s[nf][r] - m0) * scale);
      s[nf][r] = p;
      sum += p;
    }
    #pragma unroll
    for (int d = 1; d < 16; d <<= 1) sum += __shfl_xor(sum, d);
    inv[r] = 1.0f / sum;
  }

  #pragma unroll
  for (int r = 0; r < 4; ++r) {
    const int m = w * 16 + kg * 4 + r;
    #pragma unroll
    for (int nf = 0; nf < 4; ++nf) {
      const int bo = m * 128 + (nf * 16 + fr) * 2;
      *(unsigned short*)((char*)Ps + (bo ^ ((m & 7) << 4))) = bf16_of(s[nf][r] * inv[r]);
    }
  }
  __syncthreads();

  f32x4 oa[4] = {};
  #pragma unroll
  for (int kt = 0; kt < 2; ++kt) {
    const int kb = kt * 64 + kg * 16;
    const int rp = w * 16 + fr;
    bf16x8 ap = *(const bf16x8*)((const char*)Ps + rp * 128 + (kb ^ ((rp & 7) << 4)));
    #pragma unroll
    for (int df = 0; df < 4; ++df) {
      const int rv = df * 16 + fr;
      bf16x8 bv = *(const bf16x8*)((const char*)Vt + rv * 128 + (kb ^ ((rv & 7) << 4)));
      oa[df] = __builtin_amdgcn_mfma_f32_16x16x32_bf16(ap, bv, oa[df], 0, 0, 0);
    }
  }
  #pragma unroll
  for (int df = 0; df < 4; ++df) {
    #pragma unroll
    for (int r = 0; r < 4; ++r) {
      const size_t row = mbase + w * 16 + kg * 4 + r;
      const int col = h * 64 + df * 16 + fr;
      o[row * 1024 + col] = bf16_of(oa[df][r]);
    }
  }
}

// ---------------- launch ----------------
extern "C" void kernel_launch(void* const* d_in, const int* in_sizes, int n_in,
                              void* d_out, int out_size, void* d_ws, size_t ws_size,
                              hipStream_t stream) {
  const float* x     = (const float*)d_in[0];
  const float* w_qkv = (const float*)d_in[1];
  const float* w_out = (const float*)d_in[2];
  const float* b_out = (const float*)d_in[3];
  char* ws = (char*)d_ws;
  const size_t SZ_X  = (size_t)16384 * 1024 * 2;
  const size_t SZ_WQ = (size_t)3072 * 1024 * 2;
  const size_t SZ_WO = (size_t)1024 * 1024 * 2;
  unsigned short* xb  = (unsigned short*)ws;
  unsigned short* wqb = (unsigned short*)(ws + SZ_X);
  unsigned short* wob = (unsigned short*)(ws + SZ_X + SZ_WQ);
  unsigned short* qkv = (unsigned short*)(ws + SZ_X + SZ_WQ + SZ_WO);
  unsigned short* ob  = xb;  // alias: x_bf16 dead after GEMM1

  cvt_f32_bf16<<<2048, 256, 0, stream>>>(x, xb, 16384 * 1024 / 4);
  cvt_f32_bf16<<<512, 256, 0, stream>>>(w_qkv, wqb, 3072 * 1024 / 4);
  cvt_f32_bf16<<<256, 256, 0, stream>>>(w_out, wob, 1024 * 1024 / 4);
  // qkv[16384,3072] = x_bf16 @ w_qkv^T
  gemm256<0,0><<<dim3(768), 512, 0, stream>>>(xb, wqb, qkv, nullptr, 16384, 3072, 1024);
  // block-local attention -> o[16384,1024]
  attn_block<<<dim3(64, 16, 4), 256, 0, stream>>>(qkv, ob);
  // out[16384,1024] = o @ w_out^T + b_out  (fp32)
  gemm256<1,1><<<dim3(256), 512, 0, stream>>>(ob, wob, d_out, b_out, 16384, 1024, 1024);
}

// Round 3
// 197.576 us; speedup vs baseline: 1.0768x; 1.0768x over previous
//
#include <hip/hip_runtime.h>
#include <stdint.h>

typedef __attribute__((ext_vector_type(8))) short bf16x8;
typedef __attribute__((ext_vector_type(4))) float f32x4;

__device__ __forceinline__ unsigned short bf16_of(float f) {
  union { float f; uint32_t u; } x; x.f = f;
  uint32_t r = x.u + 0x7fffu + ((x.u >> 16) & 1u);
  return (unsigned short)(r >> 16);
}

#define GLD16(gp, lp) __builtin_amdgcn_global_load_lds( \
    (const __attribute__((address_space(1))) uint32_t*)(gp), \
    (__attribute__((address_space(3))) uint32_t*)(lp), 16, 0, 0)

#define BAR() do { asm volatile("" ::: "memory"); __builtin_amdgcn_s_barrier(); asm volatile("" ::: "memory"); } while (0)

// ---------------- f32 -> bf16 convert (vectorized) ----------------
__global__ void cvt_f32_bf16(const float* __restrict__ src,
                             unsigned short* __restrict__ dst, int n4) {
  int i = blockIdx.x * blockDim.x + threadIdx.x;
  int stride = gridDim.x * blockDim.x;
  for (int j = i; j < n4; j += stride) {
    float4 f = ((const float4*)src)[j];
    union { unsigned short s[4]; uint2 v; } u;
    u.s[0] = bf16_of(f.x); u.s[1] = bf16_of(f.y);
    u.s[2] = bf16_of(f.z); u.s[3] = bf16_of(f.w);
    ((uint2*)dst)[j] = u.v;
  }
}

// ------------- persistent 256x256 8-phase GEMM: C = A[M,K] * B[N,K]^T -------
// grid = 256 blocks (1/CU), NSEG output tiles per block. 8 waves (2M x 4N).
// BK=64, 128KB LDS dbuf. Deep pipeline: 3 half-tiles in flight, vmcnt(6).
// Slots: B0(G+1)@ph0, A0(G+2)@ph1, B1(G+2)@ph2, A1(G+2)@ph3. b0 cached in regs
// (phase 3 has zero LDS reads). Boundary wait once per K-tile.
template<int BIAS, int OUTF32, int GW, int NSEG>
__global__ __launch_bounds__(512, 2)
void gemm256p(const unsigned short* __restrict__ A,
              const unsigned short* __restrict__ B,
              void* __restrict__ C, const float* __restrict__ bias,
              int N, int K)
{
  __shared__ __align__(1024) unsigned short sm[65536];  // 128 KB
  char* const smb = (char*)sm;
  const int tid = threadIdx.x, w = tid >> 6, lane = tid & 63;
  const int wm = w >> 2, wn = w & 3;
  const int fr = lane & 15, kg = lane >> 4;
  const int swz = (fr & 7) << 4;
  const int srow = lane >> 3, sslot = lane & 7;
  const int cXcd = blockIdx.x & 7, iIdx = blockIdx.x >> 3;
  const int NT_tot = NSEG * 16;  // K = 1024 per output tile (16 K-steps)

  // tile-id decode: XCD c owns tiles [c*32*NSEG, ...+32*NSEG), grouped GW n-cols
  auto tileMN = [&](int s, int& mt, int& nt) {
    const int T = cXcd * (32 * NSEG) + s * 32 + iIdx;
    const int g = T / (64 * GW), rr = T % (64 * GW);
    mt = rr / GW; nt = g * GW + rr % GW;
  };

  // stage one 16KB half-tile (2 x GLD16/thread) for global K-step u
  auto STAGE = [&](int u, int opnd, int half) {
    int mt, nt; tileMN(u >> 4, mt, nt);
    const unsigned short* G_ = opnd ? B : A;
    const int grow0 = (opnd ? nt : mt) << 8;
    char* region = smb + opnd * 65536 + (u & 1) * 32768 + half * 16384;
    const int k0 = (u & 15) << 6;
    #pragma unroll
    for (int i2 = 0; i2 < 2; ++i2) {
      const int c = i2 * 8 + w;
      const int row = half * 128 + c * 8 + srow;
      const int slot = sslot ^ srow;
      GLD16(G_ + (size_t)(grow0 + row) * K + k0 + slot * 8, region + c * 1024);
    }
  };
  auto LDA = [&](char* Ab, int j, int ks) -> bf16x8 {
    const int r = 32 * j + 16 * wm + fr;
    return *(const bf16x8*)(Ab + r * 128 + ((ks * 64 + kg * 16) ^ swz));
  };
  auto LDB = [&](char* Bb, int l, int ks) -> bf16x8 {
    const int r = 64 * l + 16 * wn + fr;
    return *(const bf16x8*)(Bb + r * 128 + ((ks * 64 + kg * 16) ^ swz));
  };

  f32x4 acc[8][4] = {};

  // prologue: tile0 all halves + tile1 {A0,B1,A1}; retire tile0, leave 3 in flight
  STAGE(0, 0, 0); STAGE(0, 1, 0); STAGE(0, 0, 1); STAGE(0, 1, 1);
  STAGE(1, 0, 0); STAGE(1, 1, 1); STAGE(1, 0, 1);
  asm volatile("s_waitcnt vmcnt(6)" ::: "memory");
  BAR();

  for (int s = 0; s < NSEG; ++s) {
    for (int tt = 0; tt < 16; ++tt) {
      const int G = s * 16 + tt;
      char* Ab = smb + (G & 1) * 32768;
      char* Bb = smb + 65536 + (G & 1) * 32768;
      bf16x8 a[4][2], b[2][2], b0[2][2];

      // ---- phase 0: Q1 = A-half0 x B-half0 (b0 cached for phase 3)
      #pragma unroll
      for (int j = 0; j < 4; ++j) { a[j][0] = LDA(Ab, j, 0); a[j][1] = LDA(Ab, j, 1); }
      #pragma unroll
      for (int l = 0; l < 2; ++l) { b0[l][0] = LDB(Bb, l, 0); b0[l][1] = LDB(Bb, l, 1); }
      if (G + 1 < NT_tot) STAGE(G + 1, 1, 0);          // B0(G+1)
      BAR();
      __builtin_amdgcn_s_setprio(1);
      #pragma unroll
      for (int j = 0; j < 4; ++j)
        #pragma unroll
        for (int l = 0; l < 2; ++l) {
          acc[j][l] = __builtin_amdgcn_mfma_f32_16x16x32_bf16(a[j][0], b0[l][0], acc[j][l], 0, 0, 0);
          acc[j][l] = __builtin_amdgcn_mfma_f32_16x16x32_bf16(a[j][1], b0[l][1], acc[j][l], 0, 0, 0);
        }
      __builtin_amdgcn_s_setprio(0);
      BAR();

      // ---- phase 1: Q2 = A-half0 x B-half1
      #pragma unroll
      for (int l = 0; l < 2; ++l) { b[l][0] = LDB(Bb, l + 2, 0); b[l][1] = LDB(Bb, l + 2, 1); }
      if (G + 2 < NT_tot) STAGE(G + 2, 0, 0);          // A0(G+2)
      BAR();
      __builtin_amdgcn_s_setprio(1);
      #pragma unroll
      for (int j = 0; j < 4; ++j)
        #pragma unroll
        for (int l = 0; l < 2; ++l) {
          acc[j][l + 2] = __builtin_amdgcn_mfma_f32_16x16x32_bf16(a[j][0], b[l][0], acc[j][l + 2], 0, 0, 0);
          acc[j][l + 2] = __builtin_amdgcn_mfma_f32_16x16x32_bf16(a[j][1], b[l][1], acc[j][l + 2], 0, 0, 0);
        }
      __builtin_amdgcn_s_setprio(0);
      BAR();

      // ---- phase 2: Q3 = A-half1 x B-half1
      #pragma unroll
      for (int j = 0; j < 4; ++j) { a[j][0] = LDA(Ab, j + 4, 0); a[j][1] = LDA(Ab, j + 4, 1); }
      if (G + 2 < NT_tot) STAGE(G + 2, 1, 1);          // B1(G+2)
      BAR();
      __builtin_amdgcn_s_setprio(1);
      #pragma unroll
      for (int j = 0; j < 4; ++j)
        #pragma unroll
        for (int l = 0; l < 2; ++l) {
          acc[j + 4][l + 2] = __builtin_amdgcn_mfma_f32_16x16x32_bf16(a[j][0], b[l][0], acc[j + 4][l + 2], 0, 0, 0);
          acc[j + 4][l + 2] = __builtin_amdgcn_mfma_f32_16x16x32_bf16(a[j][1], b[l][1], acc[j + 4][l + 2], 0, 0, 0);
        }
      __builtin_amdgcn_s_setprio(0);
      BAR();

      // ---- phase 3: Q4 = A-half1 x B-half0 (cached b0; zero LDS reads)
      if (G + 2 < NT_tot) STAGE(G + 2, 0, 1);          // A1(G+2)
      BAR();
      __builtin_amdgcn_s_setprio(1);
      #pragma unroll
      for (int j = 0; j < 4; ++j)
        #pragma unroll
        for (int l = 0; l < 2; ++l) {
          acc[j + 4][l] = __builtin_amdgcn_mfma_f32_16x16x32_bf16(a[j][0], b0[l][0], acc[j + 4][l], 0, 0, 0);
          acc[j + 4][l] = __builtin_amdgcn_mfma_f32_16x16x32_bf16(a[j][1], b0[l][1], acc[j + 4][l], 0, 0, 0);
        }
      __builtin_amdgcn_s_setprio(0);
      // boundary: retire tile G+1's 4 halves; keep {A0,B1,A1}(G+2) in flight
      if (G == NT_tot - 2)      { asm volatile("s_waitcnt vmcnt(0)" ::: "memory"); }
      else if (G < NT_tot - 2)  { asm volatile("s_waitcnt vmcnt(6)" ::: "memory"); }
      BAR();
    }

    // ---- segment epilogue: write this tile's C, reset acc
    int mt, nt; tileMN(s, mt, nt);
    const int bm0 = mt << 8, bn0 = nt << 8;
    #pragma unroll
    for (int l = 0; l < 4; ++l) {
      const int col = bn0 + 64 * l + 16 * wn + fr;
      float bb = 0.0f;
      if (BIAS && OUTF32) bb = bias[col];
      #pragma unroll
      for (int j = 0; j < 8; ++j) {
        const int row0 = bm0 + 32 * j + 16 * wm + kg * 4;
        #pragma unroll
        for (int rr = 0; rr < 4; ++rr) {
          if (OUTF32)
            ((float*)C)[(size_t)(row0 + rr) * N + col] = acc[j][l][rr] + bb;
          else
            ((unsigned short*)C)[(size_t)(row0 + rr) * N + col] = bf16_of(acc[j][l][rr]);
        }
      }
    }
    #pragma unroll
    for (int j = 0; j < 8; ++j)
      #pragma unroll
      for (int l = 0; l < 4; ++l)
        acc[j][l] = f32x4{0.f, 0.f, 0.f, 0.f};
  }
}

// ---------------- block-local attention: one (b,h,g) 64x64 block per WG ----
__global__ __launch_bounds__(256, 2)
void attn_block(const unsigned short* __restrict__ qkv,
                unsigned short* __restrict__ o)
{
  __shared__ __align__(1024) unsigned short Qs[64 * 64];
  __shared__ __align__(1024) unsigned short Ks[64 * 64];
  __shared__ __align__(1024) unsigned short Vt[64 * 64];
  __shared__ __align__(1024) unsigned short Ps[64 * 64];
  const int tid = threadIdx.x, w = tid >> 6, lane = tid & 63;
  const int g = blockIdx.x, h = blockIdx.y, b = blockIdx.z;
  const size_t mbase = (size_t)b * 4096 + (size_t)g * 64;
  const unsigned short* qg = qkv + mbase * 3072 + h * 64;
  const unsigned short* kgl = qkv + mbase * 3072 + 1024 + h * 64;
  const unsigned short* vg = qkv + mbase * 3072 + 2048 + h * 64;

  #pragma unroll
  for (int i = 0; i < 2; ++i) {
    const int chunk = i * 4 + w;
    const int row = chunk * 8 + (lane >> 3);
    const int c8 = (lane & 7) ^ (row & 7);
    GLD16(qg + (size_t)row * 3072 + c8 * 8, (char*)Qs + chunk * 1024);
    GLD16(kgl + (size_t)row * 3072 + c8 * 8, (char*)Ks + chunk * 1024);
  }
  #pragma unroll
  for (int i = 0; i < 2; ++i) {
    const int c = i * 256 + tid;
    const int n = c >> 3, d0 = (c & 7) * 8;
    bf16x8 v = *(const bf16x8*)(vg + (size_t)n * 3072 + d0);
    #pragma unroll
    for (int j = 0; j < 8; ++j) {
      const int d = d0 + j;
      const int bo = d * 128 + n * 2;
      *(unsigned short*)((char*)Vt + (bo ^ ((d & 7) << 4))) = (unsigned short)v[j];
    }
  }
  __syncthreads();

  const int fr = lane & 15, kg = lane >> 4;
  f32x4 s[4] = {};
  #pragma unroll
  for (int kt = 0; kt < 2; ++kt) {
    const int kb = kt * 64 + kg * 16;
    const int rq = w * 16 + fr;
    bf16x8 aq = *(const bf16x8*)((const char*)Qs + rq * 128 + (kb ^ ((rq & 7) << 4)));
    #pragma unroll
    for (int nf = 0; nf < 4; ++nf) {
      const int rk = nf * 16 + fr;
      bf16x8 bk = *(const bf16x8*)((const char*)Ks + rk * 128 + (kb ^ ((rk & 7) << 4)));
      s[nf] = __builtin_amdgcn_mfma_f32_16x16x32_bf16(aq, bk, s[nf], 0, 0, 0);
    }
  }

  const float scale = 0.125f;
  float inv[4];
  #pragma unroll
  for (int r = 0; r < 4; ++r) {
    float m0 = fmaxf(fmaxf(s[0][r], s[1][r]), fmaxf(s[2][r], s[3][r]));
    #pragma unroll
    for (int d = 1; d < 16; d <<= 1) m0 = fmaxf(m0, __shfl_xor(m0, d));
    float sum = 0.0f;
    #pragma unroll
    for (int nf = 0; nf < 4; ++nf) {
      float p = __expf((s[nf][r] - m0) * scale);
      s[nf][r] = p;
      sum += p;
    }
    #pragma unroll
    for (int d = 1; d < 16; d <<= 1) sum += __shfl_xor(sum, d);
    inv[r] = 1.0f / sum;
  }

  #pragma unroll
  for (int r = 0; r < 4; ++r) {
    const int m = w * 16 + kg * 4 + r;
    #pragma unroll
    for (int nf = 0; nf < 4; ++nf) {
      const int bo = m * 128 + (nf * 16 + fr) * 2;
      *(unsigned short*)((char*)Ps + (bo ^ ((m & 7) << 4))) = bf16_of(s[nf][r] * inv[r]);
    }
  }
  __syncthreads();

  f32x4 oa[4] = {};
  #pragma unroll
  for (int kt = 0; kt < 2; ++kt) {
    const int kb = kt * 64 + kg * 16;
    const int rp = w * 16 + fr;
    bf16x8 ap = *(const bf16x8*)((const char*)Ps + rp * 128 + (kb ^ ((rp & 7) << 4)));
    #pragma unroll
    for (int df = 0; df < 4; ++df) {
      const int rv = df * 16 + fr;
      bf16x8 bv = *(const bf16x8*)((const char*)Vt + rv * 128 + (kb ^ ((rv & 7) << 4)));
      oa[df] = __builtin_amdgcn_mfma_f32_16x16x32_bf16(ap, bv, oa[df], 0, 0, 0);
    }
  }
  #pragma unroll
  for (int df = 0; df < 4; ++df) {
    #pragma unroll
    for (int r = 0; r < 4; ++r) {
      const size_t row = mbase + w * 16 + kg * 4 + r;
      const int col = h * 64 + df * 16 + fr;
      o[row * 1024 + col] = bf16_of(oa[df][r]);
    }
  }
}

// ---------------- launch ----------------
extern "C" void kernel_launch(void* const* d_in, const int* in_sizes, int n_in,
                              void* d_out, int out_size, void* d_ws, size_t ws_size,
                              hipStream_t stream) {
  const float* x     = (const float*)d_in[0];
  const float* w_qkv = (const float*)d_in[1];
  const float* w_out = (const float*)d_in[2];
  const float* b_out = (const float*)d_in[3];
  char* ws = (char*)d_ws;
  const size_t SZ_X  = (size_t)16384 * 1024 * 2;
  const size_t SZ_WQ = (size_t)3072 * 1024 * 2;
  const size_t SZ_WO = (size_t)1024 * 1024 * 2;
  unsigned short* xb  = (unsigned short*)ws;
  unsigned short* wqb = (unsigned short*)(ws + SZ_X);
  unsigned short* wob = (unsigned short*)(ws + SZ_X + SZ_WQ);
  unsigned short* qkv = (unsigned short*)(ws + SZ_X + SZ_WQ + SZ_WO);
  unsigned short* ob  = xb;  // alias: x_bf16 dead after GEMM1

  cvt_f32_bf16<<<2048, 256, 0, stream>>>(x, xb, 16384 * 1024 / 4);
  cvt_f32_bf16<<<512, 256, 0, stream>>>(w_qkv, wqb, 3072 * 1024 / 4);
  cvt_f32_bf16<<<256, 256, 0, stream>>>(w_out, wob, 1024 * 1024 / 4);
  // qkv[16384,3072] = x_bf16 @ w_qkv^T   (persistent: 3 tiles/block, GW=6)
  gemm256p<0,0,6,3><<<dim3(256), 512, 0, stream>>>(xb, wqb, qkv, nullptr, 3072, 1024);
  // block-local attention -> o[16384,1024]
  attn_block<<<dim3(64, 16, 4), 256, 0, stream>>>(qkv, ob);
  // out[16384,1024] = o @ w_out^T + b_out  (fp32; 1 tile/block, GW=4)
  gemm256p<1,1,4,1><<<dim3(256), 512, 0, stream>>>(ob, wob, d_out, b_out, 1024, 1024);
}

// Round 4
// 185.375 us; speedup vs baseline: 1.1477x; 1.0658x over previous
//
#include <hip/hip_runtime.h>
#include <stdint.h>

typedef __attribute__((ext_vector_type(8))) short bf16x8;
typedef __attribute__((ext_vector_type(4))) float f32x4;

__device__ __forceinline__ unsigned short bf16_of(float f) {
  union { float f; uint32_t u; } x; x.f = f;
  uint32_t r = x.u + 0x7fffu + ((x.u >> 16) & 1u);
  return (unsigned short)(r >> 16);
}

#define GLD16(gp, lp) __builtin_amdgcn_global_load_lds( \
    (const __attribute__((address_space(1))) uint32_t*)(gp), \
    (__attribute__((address_space(3))) uint32_t*)(lp), 16, 0, 0)

#define BAR() do { asm volatile("" ::: "memory"); __builtin_amdgcn_s_barrier(); asm volatile("" ::: "memory"); } while (0)

// ---------------- f32 -> bf16 convert (vectorized) ----------------
__global__ void cvt_f32_bf16(const float* __restrict__ src,
                             unsigned short* __restrict__ dst, int n4) {
  int i = blockIdx.x * blockDim.x + threadIdx.x;
  int stride = gridDim.x * blockDim.x;
  for (int j = i; j < n4; j += stride) {
    float4 f = ((const float4*)src)[j];
    union { unsigned short s[4]; uint2 v; } u;
    u.s[0] = bf16_of(f.x); u.s[1] = bf16_of(f.y);
    u.s[2] = bf16_of(f.z); u.s[3] = bf16_of(f.w);
    ((uint2*)dst)[j] = u.v;
  }
}

// ------------- persistent 256x256 GEMM, 2-barrier K-tile: C = A*B^T ---------
// 8 waves (2M x 4N), BK=64, 128KB LDS dbuf. Stages 1-ahead (always inactive
// buffer -> no mid-tile overwrite hazard). Per K-tile: vmcnt(2)+BarA
// [A0/B0/B1 visible], free-run H1 (Q1,Q2: 16 ds_read + 32 MFMA), vmcnt(8)+BarB
// [A1 visible], free-run H2 (Q3,Q4: 8 ds_read + 32 MFMA). No other barriers:
// LDS reads overlap MFMA via wave drift + compiler scheduling.
template<int BIAS, int OUTF32, int GW, int NSEG>
__global__ __launch_bounds__(512, 2)
void gemm256f(const unsigned short* __restrict__ A,
              const unsigned short* __restrict__ B,
              void* __restrict__ C, const float* __restrict__ bias,
              int N, int K)
{
  __shared__ __align__(1024) unsigned short sm[65536];  // 128 KB
  char* const smb = (char*)sm;
  const int tid = threadIdx.x, w = tid >> 6, lane = tid & 63;
  const int wm = w >> 2, wn = w & 3;
  const int fr = lane & 15, kg = lane >> 4;
  const int swz = (fr & 7) << 4;
  const int srow = lane >> 3, sslot = lane & 7;
  const int cXcd = blockIdx.x & 7, iIdx = blockIdx.x >> 3;
  const int NT_tot = NSEG * 16;  // K = 1024 per output tile (16 K-steps)

  auto tileMN = [&](int s, int& mt, int& nt) {
    const int T = cXcd * (32 * NSEG) + s * 32 + iIdx;
    const int g = T / (64 * GW), rr = T % (64 * GW);
    mt = rr / GW; nt = g * GW + rr % GW;
  };

  // stage one 16KB half-tile (2 x GLD16/thread) for global K-step u
  auto STAGE = [&](int u, int opnd, int half) {
    int mt, nt; tileMN(u >> 4, mt, nt);
    const unsigned short* G_ = opnd ? B : A;
    const int grow0 = (opnd ? nt : mt) << 8;
    char* region = smb + opnd * 65536 + (u & 1) * 32768 + half * 16384;
    const int k0 = (u & 15) << 6;
    #pragma unroll
    for (int i2 = 0; i2 < 2; ++i2) {
      const int c = i2 * 8 + w;
      const int row = half * 128 + c * 8 + srow;
      const int slot = sslot ^ srow;
      GLD16(G_ + (size_t)(grow0 + row) * K + k0 + slot * 8, region + c * 1024);
    }
  };
  auto LDA = [&](char* Ab, int j, int ks) -> bf16x8 {
    const int r = 32 * j + 16 * wm + fr;
    return *(const bf16x8*)(Ab + r * 128 + ((ks * 64 + kg * 16) ^ swz));
  };
  auto LDB = [&](char* Bb, int l, int ks) -> bf16x8 {
    const int r = 64 * l + 16 * wn + fr;
    return *(const bf16x8*)(Bb + r * 128 + ((ks * 64 + kg * 16) ^ swz));
  };

  f32x4 acc[8][4] = {};

  // prologue: stage all 4 halves of tile 0 (issue order B0,A0,B1,A1)
  STAGE(0, 1, 0); STAGE(0, 0, 0); STAGE(0, 1, 1); STAGE(0, 0, 1);

  for (int s = 0; s < NSEG; ++s) {
    for (int tt = 0; tt < 16; ++tt) {
      const int T = s * 16 + tt;
      char* Ab = smb + (T & 1) * 32768;
      char* Bb = smb + 65536 + (T & 1) * 32768;
      bf16x8 a[4][2], b0[2][2], b1[2][2];

      // ---- BarA: A0,B0,B1(T) landed (own loads retired to <=2) + visible
      asm volatile("s_waitcnt vmcnt(2)" ::: "memory");
      BAR();

      // issue all 4 stages for T+1 (inactive buffer; 8 loads)
      if (T + 1 < NT_tot) {
        STAGE(T + 1, 1, 0);  // B0
        STAGE(T + 1, 0, 0);  // A0
        STAGE(T + 1, 1, 1);  // B1
        STAGE(T + 1, 0, 1);  // A1
      }

      // ---- H1: Q1 = A0 x B0, Q2 = A0 x B1 (free-running)
      #pragma unroll
      for (int l = 0; l < 2; ++l) { b0[l][0] = LDB(Bb, l, 0); b0[l][1] = LDB(Bb, l, 1); }
      #pragma unroll
      for (int j = 0; j < 4; ++j) { a[j][0] = LDA(Ab, j, 0); a[j][1] = LDA(Ab, j, 1); }
      #pragma unroll
      for (int l = 0; l < 2; ++l) { b1[l][0] = LDB(Bb, l + 2, 0); b1[l][1] = LDB(Bb, l + 2, 1); }
      __builtin_amdgcn_s_setprio(1);
      #pragma unroll
      for (int j = 0; j < 4; ++j)
        #pragma unroll
        for (int l = 0; l < 2; ++l) {
          acc[j][l] = __builtin_amdgcn_mfma_f32_16x16x32_bf16(a[j][0], b0[l][0], acc[j][l], 0, 0, 0);
          acc[j][l] = __builtin_amdgcn_mfma_f32_16x16x32_bf16(a[j][1], b0[l][1], acc[j][l], 0, 0, 0);
        }
      #pragma unroll
      for (int j = 0; j < 4; ++j)
        #pragma unroll
        for (int l = 0; l < 2; ++l) {
          acc[j][l + 2] = __builtin_amdgcn_mfma_f32_16x16x32_bf16(a[j][0], b1[l][0], acc[j][l + 2], 0, 0, 0);
          acc[j][l + 2] = __builtin_amdgcn_mfma_f32_16x16x32_bf16(a[j][1], b1[l][1], acc[j][l + 2], 0, 0, 0);
        }
      __builtin_amdgcn_s_setprio(0);

      // ---- BarB: A1(T) landed (retire own A1(T): outstanding <= 8 = T+1's) + visible
      asm volatile("s_waitcnt vmcnt(8)" ::: "memory");
      BAR();

      // ---- H2: Q3 = A1 x B1, Q4 = A1 x B0 (b0,b1 cached in regs)
      #pragma unroll
      for (int j = 0; j < 4; ++j) { a[j][0] = LDA(Ab, j + 4, 0); a[j][1] = LDA(Ab, j + 4, 1); }
      __builtin_amdgcn_s_setprio(1);
      #pragma unroll
      for (int j = 0; j < 4; ++j)
        #pragma unroll
        for (int l = 0; l < 2; ++l) {
          acc[j + 4][l + 2] = __builtin_amdgcn_mfma_f32_16x16x32_bf16(a[j][0], b1[l][0], acc[j + 4][l + 2], 0, 0, 0);
          acc[j + 4][l + 2] = __builtin_amdgcn_mfma_f32_16x16x32_bf16(a[j][1], b1[l][1], acc[j + 4][l + 2], 0, 0, 0);
        }
      #pragma unroll
      for (int j = 0; j < 4; ++j)
        #pragma unroll
        for (int l = 0; l < 2; ++l) {
          acc[j + 4][l] = __builtin_amdgcn_mfma_f32_16x16x32_bf16(a[j][0], b0[l][0], acc[j + 4][l], 0, 0, 0);
          acc[j + 4][l] = __builtin_amdgcn_mfma_f32_16x16x32_bf16(a[j][1], b0[l][1], acc[j + 4][l], 0, 0, 0);
        }
      __builtin_amdgcn_s_setprio(0);
    }

    // ---- segment epilogue (overlaps next tile's staging latency)
    int mt, nt; tileMN(s, mt, nt);
    const int bm0 = mt << 8, bn0 = nt << 8;
    #pragma unroll
    for (int l = 0; l < 4; ++l) {
      const int col = bn0 + 64 * l + 16 * wn + fr;
      float bb = 0.0f;
      if (BIAS && OUTF32) bb = bias[col];
      #pragma unroll
      for (int j = 0; j < 8; ++j) {
        const int row0 = bm0 + 32 * j + 16 * wm + kg * 4;
        #pragma unroll
        for (int rr = 0; rr < 4; ++rr) {
          if (OUTF32)
            ((float*)C)[(size_t)(row0 + rr) * N + col] = acc[j][l][rr] + bb;
          else
            ((unsigned short*)C)[(size_t)(row0 + rr) * N + col] = bf16_of(acc[j][l][rr]);
        }
      }
    }
    #pragma unroll
    for (int j = 0; j < 8; ++j)
      #pragma unroll
      for (int l = 0; l < 4; ++l)
        acc[j][l] = f32x4{0.f, 0.f, 0.f, 0.f};
  }
}

// ---------------- block-local attention: one (b,h,g) 64x64 block per WG ----
__global__ __launch_bounds__(256, 2)
void attn_block(const unsigned short* __restrict__ qkv,
                unsigned short* __restrict__ o)
{
  __shared__ __align__(1024) unsigned short Qs[64 * 64];
  __shared__ __align__(1024) unsigned short Ks[64 * 64];
  __shared__ __align__(1024) unsigned short Vt[64 * 64];
  __shared__ __align__(1024) unsigned short Ps[64 * 64];
  const int tid = threadIdx.x, w = tid >> 6, lane = tid & 63;
  const int g = blockIdx.x, h = blockIdx.y, b = blockIdx.z;
  const size_t mbase = (size_t)b * 4096 + (size_t)g * 64;
  const unsigned short* qg = qkv + mbase * 3072 + h * 64;
  const unsigned short* kgl = qkv + mbase * 3072 + 1024 + h * 64;
  const unsigned short* vg = qkv + mbase * 3072 + 2048 + h * 64;

  #pragma unroll
  for (int i = 0; i < 2; ++i) {
    const int chunk = i * 4 + w;
    const int row = chunk * 8 + (lane >> 3);
    const int c8 = (lane & 7) ^ (row & 7);
    GLD16(qg + (size_t)row * 3072 + c8 * 8, (char*)Qs + chunk * 1024);
    GLD16(kgl + (size_t)row * 3072 + c8 * 8, (char*)Ks + chunk * 1024);
  }
  #pragma unroll
  for (int i = 0; i < 2; ++i) {
    const int c = i * 256 + tid;
    const int n = c >> 3, d0 = (c & 7) * 8;
    bf16x8 v = *(const bf16x8*)(vg + (size_t)n * 3072 + d0);
    #pragma unroll
    for (int j = 0; j < 8; ++j) {
      const int d = d0 + j;
      const int bo = d * 128 + n * 2;
      *(unsigned short*)((char*)Vt + (bo ^ ((d & 7) << 4))) = (unsigned short)v[j];
    }
  }
  __syncthreads();

  const int fr = lane & 15, kg = lane >> 4;
  f32x4 s[4] = {};
  #pragma unroll
  for (int kt = 0; kt < 2; ++kt) {
    const int kb = kt * 64 + kg * 16;
    const int rq = w * 16 + fr;
    bf16x8 aq = *(const bf16x8*)((const char*)Qs + rq * 128 + (kb ^ ((rq & 7) << 4)));
    #pragma unroll
    for (int nf = 0; nf < 4; ++nf) {
      const int rk = nf * 16 + fr;
      bf16x8 bk = *(const bf16x8*)((const char*)Ks + rk * 128 + (kb ^ ((rk & 7) << 4)));
      s[nf] = __builtin_amdgcn_mfma_f32_16x16x32_bf16(aq, bk, s[nf], 0, 0, 0);
    }
  }

  const float scale = 0.125f;
  float inv[4];
  #pragma unroll
  for (int r = 0; r < 4; ++r) {
    float m0 = fmaxf(fmaxf(s[0][r], s[1][r]), fmaxf(s[2][r], s[3][r]));
    #pragma unroll
    for (int d = 1; d < 16; d <<= 1) m0 = fmaxf(m0, __shfl_xor(m0, d));
    float sum = 0.0f;
    #pragma unroll
    for (int nf = 0; nf < 4; ++nf) {
      float p = __expf((s[nf][r] - m0) * scale);
      s[nf][r] = p;
      sum += p;
    }
    #pragma unroll
    for (int d = 1; d < 16; d <<= 1) sum += __shfl_xor(sum, d);
    inv[r] = 1.0f / sum;
  }

  #pragma unroll
  for (int r = 0; r < 4; ++r) {
    const int m = w * 16 + kg * 4 + r;
    #pragma unroll
    for (int nf = 0; nf < 4; ++nf) {
      const int bo = m * 128 + (nf * 16 + fr) * 2;
      *(unsigned short*)((char*)Ps + (bo ^ ((m & 7) << 4))) = bf16_of(s[nf][r] * inv[r]);
    }
  }
  __syncthreads();

  f32x4 oa[4] = {};
  #pragma unroll
  for (int kt = 0; kt < 2; ++kt) {
    const int kb = kt * 64 + kg * 16;
    const int rp = w * 16 + fr;
    bf16x8 ap = *(const bf16x8*)((const char*)Ps + rp * 128 + (kb ^ ((rp & 7) << 4)));
    #pragma unroll
    for (int df = 0; df < 4; ++df) {
      const int rv = df * 16 + fr;
      bf16x8 bv = *(const bf16x8*)((const char*)Vt + rv * 128 + (kb ^ ((rv & 7) << 4)));
      oa[df] = __builtin_amdgcn_mfma_f32_16x16x32_bf16(ap, bv, oa[df], 0, 0, 0);
    }
  }
  #pragma unroll
  for (int df = 0; df < 4; ++df) {
    #pragma unroll
    for (int r = 0; r < 4; ++r) {
      const size_t row = mbase + w * 16 + kg * 4 + r;
      const int col = h * 64 + df * 16 + fr;
      o[row * 1024 + col] = bf16_of(oa[df][r]);
    }
  }
}

// ---------------- launch ----------------
extern "C" void kernel_launch(void* const* d_in, const int* in_sizes, int n_in,
                              void* d_out, int out_size, void* d_ws, size_t ws_size,
                              hipStream_t stream) {
  const float* x     = (const float*)d_in[0];
  const float* w_qkv = (const float*)d_in[1];
  const float* w_out = (const float*)d_in[2];
  const float* b_out = (const float*)d_in[3];
  char* ws = (char*)d_ws;
  const size_t SZ_X  = (size_t)16384 * 1024 * 2;
  const size_t SZ_WQ = (size_t)3072 * 1024 * 2;
  const size_t SZ_WO = (size_t)1024 * 1024 * 2;
  unsigned short* xb  = (unsigned short*)ws;
  unsigned short* wqb = (unsigned short*)(ws + SZ_X);
  unsigned short* wob = (unsigned short*)(ws + SZ_X + SZ_WQ);
  unsigned short* qkv = (unsigned short*)(ws + SZ_X + SZ_WQ + SZ_WO);
  unsigned short* ob  = xb;  // alias: x_bf16 dead after GEMM1

  cvt_f32_bf16<<<2048, 256, 0, stream>>>(x, xb, 16384 * 1024 / 4);
  cvt_f32_bf16<<<512, 256, 0, stream>>>(w_qkv, wqb, 3072 * 1024 / 4);
  cvt_f32_bf16<<<256, 256, 0, stream>>>(w_out, wob, 1024 * 1024 / 4);
  // qkv[16384,3072] = x_bf16 @ w_qkv^T   (persistent: 3 tiles/block, GW=6)
  gemm256f<0,0,6,3><<<dim3(256), 512, 0, stream>>>(xb, wqb, qkv, nullptr, 3072, 1024);
  // block-local attention -> o[16384,1024]
  attn_block<<<dim3(64, 16, 4), 256, 0, stream>>>(qkv, ob);
  // out[16384,1024] = o @ w_out^T + b_out  (fp32; 1 tile/block, GW=4)
  gemm256f<1,1,4,1><<<dim3(256), 512, 0, stream>>>(ob, wob, d_out, b_out, 1024, 1024);
}